// Round 10
// baseline (403.170 us; speedup 1.0000x reference)
//
#include <hip/hip_runtime.h>

#define NN   100000
#define TL   128
#define OC   5
#define KW   7
#define ST   3
#define CL   41          // (128-7)/3+1
#define FLAT 205         // 5*41
#define EMB  32
#define HID  16
#define NE   3200000

#define JPAD 208                 // FLAT padded to multiple of 8 (zero weight rows)
#define SXW  1032                // per-wave s_x slice (8*129; max read idx 126 -> no pad)

#define BBUCK  391               // bin buckets (256 nodes each, dst>>8)
#define NPB    14336             // slots per bin bucket (mean fill ~12980, +16 sigma)
#define TILE   4096              // edges per k_bin block
#define NBIN   782               // ceil(NE/TILE)
#define CNODES 64                // nodes per gagg/sort bucket
#define NGB    1563              // ceil(NN/64)
#define NS     2560              // sorted-src capacity per 64-node bucket (mean 2048)
#define SENT   0xFFFFFFFFu       // sentinel slot (real words are < 2^26)

__device__ __forceinline__ void f4add(float4& a, const float4 v) {
    a.x += v.x; a.y += v.y; a.z += v.z; a.w += v.w;
}

// ===========================================================================
// Precompute combined weight wcTj = g1w1 @ fc_w, J-MAJOR [JPAD][16]:
// wcTj[j*16 + l] = sum_m g1w1[l,m]*fc_w[m,j]  (j<205; rows 205..207 zero).
// bc = g1w1 @ fc_b.  Also init per-bucket bin cursors gcur[b] = b*NPB.
// ===========================================================================
__global__ __launch_bounds__(256) void k_prep(
    const float* __restrict__ g1w1, const float* __restrict__ fc_w,
    const float* __restrict__ fc_b,
    float* __restrict__ wcTj, float* __restrict__ bc,
    int* __restrict__ gcur)
{
    int tid = threadIdx.x;
    for (int idx = tid; idx < JPAD * HID; idx += 256) {
        int j = idx >> 4;
        int l = idx & 15;
        float s = 0.f;
        if (j < FLAT) {
            #pragma unroll
            for (int m = 0; m < EMB; ++m)
                s = fmaf(g1w1[l * EMB + m], fc_w[m * FLAT + j], s);
        }
        wcTj[idx] = s;
    }
    if (tid < HID) {
        float s = 0.f;
        #pragma unroll
        for (int m = 0; m < EMB; ++m)
            s = fmaf(g1w1[tid * EMB + m], fc_b[m], s);
        bc[tid] = s;
    }
    for (int b = tid; b < BBUCK; b += 256)
        gcur[b] = b * NPB;
}

// ===========================================================================
// Fused Conv1d+ReLU+FC(+g1w1), REGISTER-H (no h tensor, no second phase).
// r6-r9 post-mortem: the ~70us invariant survived DS-count (r7), occupancy
// (r8) and barrier (r9) changes -> the cost is the conv->LDS->FC round-trip
// dependent path itself.  v4: 8 lanes per node; lane g computes h[j] for
// j=g,8+g,...(26 vals) and folds each IMMEDIATELY into acc[16] with the
// j-major weight row (4 float4 global loads, L1-resident 13KB).  h stays in
// registers; partial accs combined by 3-step shfl_xor butterfly (DPP);
// lane g==0 writes the node row (+bias).  LDS = s_x only (16.6KB);
// launch_bounds(256,6) -> 6 blk/CU = 24 waves/CU, VGPR cap ~85.
// Only fence: wave-local lgkmcnt(0) after x staging (r9-validated).
// ===========================================================================
__global__ __launch_bounds__(256, 6) void k_convfc(
    const float* __restrict__ x,
    const float* __restrict__ conv_w, const float* __restrict__ conv_b,
    const float* __restrict__ wcTj,  const float* __restrict__ bc,
    float* __restrict__ p1)
{
    __shared__ float s_x[4 * SXW];
    const int tid  = threadIdx.x;
    const int wv   = tid >> 6;
    const int lane = tid & 63;
    const int n    = lane >> 3;       // node within wave slice (0..7)
    const int g    = lane & 7;        // j-partition (j = g mod 8)
    const long long nw = (long long)blockIdx.x * 32 + wv * 8;  // NN=32*3125

    float* sx = s_x + wv * SXW;

    // stage this wave's 8 x-rows: 256 float4 coalesced, row-padded writes
    const float4* xv = (const float4*)(x + nw * TL);
    #pragma unroll
    for (int cc = 0; cc < 4; ++cc) {
        int f4  = cc * 64 + lane;     // 0..255
        int row = f4 >> 5;            // 0..7
        int c4  = f4 & 31;
        float4 v = xv[f4];
        float* d = sx + row * 129 + c4 * 4;
        d[0] = v.x; d[1] = v.y; d[2] = v.z; d[3] = v.w;
    }
    // wave-local fence: LDS writes retired before cross-lane reads
    asm volatile("s_waitcnt lgkmcnt(0)" ::: "memory");

    float acc[16];
    #pragma unroll
    for (int l = 0; l < 16; ++l) acc[l] = 0.f;

    const float* xrow = sx + n * 129;
    const float4* wp = (const float4*)(wcTj) + g * 4;   // row j=g
    int t = g, c = 0;
    #pragma unroll 2
    for (int jj = 0; jj < 26; ++jj) {
        if (c < OC) {
            const float* xr = xrow + t * ST;
            const float* cw = conv_w + c * KW;
            float h = conv_b[c];
            #pragma unroll
            for (int k = 0; k < KW; ++k) h = fmaf(xr[k], cw[k], h);
            h = fmaxf(h, 0.f);
            float4 w0 = wp[0], w1 = wp[1], w2 = wp[2], w3 = wp[3];
            acc[0]  = fmaf(h, w0.x, acc[0]);
            acc[1]  = fmaf(h, w0.y, acc[1]);
            acc[2]  = fmaf(h, w0.z, acc[2]);
            acc[3]  = fmaf(h, w0.w, acc[3]);
            acc[4]  = fmaf(h, w1.x, acc[4]);
            acc[5]  = fmaf(h, w1.y, acc[5]);
            acc[6]  = fmaf(h, w1.z, acc[6]);
            acc[7]  = fmaf(h, w1.w, acc[7]);
            acc[8]  = fmaf(h, w2.x, acc[8]);
            acc[9]  = fmaf(h, w2.y, acc[9]);
            acc[10] = fmaf(h, w2.z, acc[10]);
            acc[11] = fmaf(h, w2.w, acc[11]);
            acc[12] = fmaf(h, w3.x, acc[12]);
            acc[13] = fmaf(h, w3.y, acc[13]);
            acc[14] = fmaf(h, w3.z, acc[14]);
            acc[15] = fmaf(h, w3.w, acc[15]);
        }
        t += 8;
        if (t >= CL) { t -= CL; ++c; }
        wp += 32;                     // advance 8 weight rows (8*16 floats)
    }

    // 8-lane butterfly reduce across the j-partitions (DPP shuffles)
    #pragma unroll
    for (int l = 0; l < 16; ++l) {
        acc[l] += __shfl_xor(acc[l], 1);
        acc[l] += __shfl_xor(acc[l], 2);
        acc[l] += __shfl_xor(acc[l], 4);
    }

    if (g == 0) {
        const float4* bcv = (const float4*)bc;
        float4 b0 = bcv[0], b1 = bcv[1], b2 = bcv[2], b3 = bcv[3];
        float4* po = (float4*)(p1 + (nw + n) * HID);
        po[0] = make_float4(acc[0]  + b0.x, acc[1]  + b0.y,
                            acc[2]  + b0.z, acc[3]  + b0.w);
        po[1] = make_float4(acc[4]  + b1.x, acc[5]  + b1.y,
                            acc[6]  + b1.z, acc[7]  + b1.w);
        po[2] = make_float4(acc[8]  + b2.x, acc[9]  + b2.y,
                            acc[10] + b2.z, acc[11] + b2.w);
        po[3] = make_float4(acc[12] + b3.x, acc[13] + b3.y,
                            acc[14] + b3.z, acc[15] + b3.w);
    }
}

// ===========================================================================
// LDS-staged bucket binning v2 (unchanged, verified r6).
// ===========================================================================
__global__ __launch_bounds__(256) void k_bin(
    const int* __restrict__ ei, int* __restrict__ gcur,
    unsigned int* __restrict__ gbin)
{
    __shared__ unsigned int s_stage[TILE];                 // 16 KB
    __shared__ int s_cnt[BBUCK], s_ofs[BBUCK], s_base[BBUCK];  // 4.7 KB
    __shared__ int s_sum[256];

    const int tid = threadIdx.x;
    const int e0  = blockIdx.x * TILE;
    const int cntE = min(TILE, NE - e0);

    for (int b = tid; b < BBUCK; b += 256) s_cnt[b] = 0;
    __syncthreads();

    // P1: histogram over 391 buckets
    for (int i = tid; i < cntE; i += 256)
        atomicAdd(&s_cnt[ei[NE + e0 + i] >> 8], 1);
    __syncthreads();

    // P2a: aligned global reservation (one atomic per nonempty bucket)
    for (int b = tid; b < BBUCK; b += 256) {
        int c = s_cnt[b];
        s_base[b] = c ? atomicAdd(&gcur[b], (c + 15) & ~15) : 0;
    }

    // P2b: exclusive scan of s_cnt -> s_ofs (chunks of 2)
    int v0 = 0, v1 = 0;
    {
        int i0 = tid * 2;
        if (i0     < BBUCK) v0 = s_cnt[i0];
        if (i0 + 1 < BBUCK) v1 = s_cnt[i0 + 1];
    }
    int csum = v0 + v1;
    s_sum[tid] = csum;
    __syncthreads();
    #pragma unroll
    for (int d = 1; d < 256; d <<= 1) {
        int t = (tid >= d) ? s_sum[tid - d] : 0;
        __syncthreads();
        s_sum[tid] += t;
        __syncthreads();
    }
    {
        int run = s_sum[tid] - csum;
        int i0 = tid * 2;
        if (i0     < BBUCK) { s_ofs[i0]     = run; run += v0; }
        if (i0 + 1 < BBUCK) { s_ofs[i0 + 1] = run; }
    }
    __syncthreads();

    // P3: scatter packed (local_dst<<17)|src into LDS staging
    for (int i = tid; i < cntE; i += 256) {
        int s = ei[e0 + i];
        int d = ei[NE + e0 + i];
        int b = d >> 8;
        int pos = atomicAdd(&s_ofs[b], 1);
        s_stage[pos] = ((unsigned int)(d & 255) << 17) | (unsigned int)s;
    }
    __syncthreads();

    // P4: coalesced copy-out, sentinel-padded to aligned reservation
    const int wid = tid >> 6, lane = tid & 63;
    for (int b = wid; b < BBUCK; b += 4) {
        int cnt = s_cnt[b];
        if (!cnt) continue;
        int res = (cnt + 15) & ~15;
        int rdo = s_ofs[b] - cnt;
        int gb  = s_base[b];
        int lim = min(res, b * NPB + NPB - gb);      // overflow clamp (never hits)
        for (int j = lane; j < lim; j += 64)
            gbin[(size_t)gb + j] = (j < cnt) ? s_stage[rdo + j] : SENT;
    }
}

// ===========================================================================
// Quarter-bucket counting sort v2 (unchanged, verified r6).
// ===========================================================================
__global__ __launch_bounds__(256) void k_sort(
    const unsigned int* __restrict__ gbin, const int* __restrict__ gcur,
    int* __restrict__ goff, int* __restrict__ gsorted)
{
    __shared__ unsigned int s_m[NS];                 // 10 KB
    __shared__ int s_cnt[CNODES], s_ofs[CNODES], s_loc[CNODES];
    __shared__ int s_n;
    const int tid = threadIdx.x;
    const int b64 = blockIdx.x;
    const int bkt = b64 >> 2, q = b64 & 3;
    const int nslots = min(gcur[bkt] - bkt * NPB, NPB);
    const unsigned int* run = gbin + (size_t)bkt * NPB;

    if (tid < CNODES) s_cnt[tid] = 0;
    if (tid == 0) s_n = 0;
    __syncthreads();

    // filtered append + histogram in one pass
    for (int i = tid; i < nslots; i += 256) {
        unsigned int w = run[i];
        if (w != SENT && (int)(w >> 23) == q) {
            int p = atomicAdd(&s_n, 1);
            if (p < NS) {                            // clamp (never hits)
                s_m[p] = w;
                atomicAdd(&s_cnt[(w >> 17) & 63], 1);
            }
        }
    }
    __syncthreads();

    // inclusive Hillis-Steele scan over 64 counters
    if (tid < CNODES) s_ofs[tid] = s_cnt[tid];
    __syncthreads();
    #pragma unroll
    for (int d = 1; d < CNODES; d <<= 1) {
        int t = (tid < CNODES && tid >= d) ? s_ofs[tid - d] : 0;
        __syncthreads();
        if (tid < CNODES) s_ofs[tid] += t;
        __syncthreads();
    }
    if (tid < CNODES) {
        int inc = s_ofs[tid];
        s_loc[tid] = inc - s_cnt[tid];               // exclusive
        goff[(size_t)b64 * 65 + tid + 1] = inc;
    }
    if (tid == 0) goff[(size_t)b64 * 65] = 0;
    __syncthreads();

    // scatter srcs into block-exclusive sorted region
    const int n = min(s_n, NS);
    int* dst = gsorted + (size_t)b64 * NS;
    for (int i = tid; i < n; i += 256) {
        unsigned int w = s_m[i];
        int pos = atomicAdd(&s_loc[(w >> 17) & 63], 1);
        dst[pos] = (int)(w & 0x1FFFFu);
    }
}

// ===========================================================================
// Fused gather-aggregate + GIN MLP, ATOMIC-FREE (unchanged, verified r6).
// ===========================================================================
__global__ __launch_bounds__(256) void k_gagg1(
    const float* __restrict__ feat, const int* __restrict__ goff,
    const int* __restrict__ gsorted,
    const float* __restrict__ b1, const float* __restrict__ w2,
    const float* __restrict__ b2, const float* __restrict__ w3,
    float* __restrict__ outfeat)
{
    __shared__ float s_acc[CNODES * 16];
    __shared__ float s_w2[HID * HID], s_w3[HID * HID], s_b1[HID], s_b2[HID];
    __shared__ int s_off[CNODES + 1];
    const int tid = threadIdx.x;
    const int b   = blockIdx.x;

    s_w2[tid] = w2[tid];
    s_w3[tid] = w3[tid];
    if (tid < HID) { s_b1[tid] = b1[tid]; s_b2[tid] = b2[tid]; }
    if (tid < CNODES + 1) s_off[tid] = goff[(size_t)b * 65 + tid];
    __syncthreads();

    const int node = tid >> 2, q = tid & 3;
    const int* srcs = gsorted + (size_t)b * NS;
    const float4* pv = (const float4*)feat;
    float4 acc0 = make_float4(0.f, 0.f, 0.f, 0.f);
    float4 acc1 = make_float4(0.f, 0.f, 0.f, 0.f);
    int j = s_off[node];
    const int e = s_off[node + 1];
    for (; j + 7 < e; j += 8) {
        int s0 = srcs[j],     s1 = srcs[j + 1], s2 = srcs[j + 2], s3 = srcs[j + 3];
        int s4 = srcs[j + 4], s5 = srcs[j + 5], s6 = srcs[j + 6], s7 = srcs[j + 7];
        float4 v0 = pv[(size_t)s0 * 4 + q];
        float4 v1 = pv[(size_t)s1 * 4 + q];
        float4 v2 = pv[(size_t)s2 * 4 + q];
        float4 v3 = pv[(size_t)s3 * 4 + q];
        float4 v4 = pv[(size_t)s4 * 4 + q];
        float4 v5 = pv[(size_t)s5 * 4 + q];
        float4 v6 = pv[(size_t)s6 * 4 + q];
        float4 v7 = pv[(size_t)s7 * 4 + q];
        f4add(acc0, v0); f4add(acc1, v1); f4add(acc0, v2); f4add(acc1, v3);
        f4add(acc0, v4); f4add(acc1, v5); f4add(acc0, v6); f4add(acc1, v7);
    }
    for (; j + 3 < e; j += 4) {
        int s0 = srcs[j], s1 = srcs[j + 1], s2 = srcs[j + 2], s3 = srcs[j + 3];
        float4 v0 = pv[(size_t)s0 * 4 + q];
        float4 v1 = pv[(size_t)s1 * 4 + q];
        float4 v2 = pv[(size_t)s2 * 4 + q];
        float4 v3 = pv[(size_t)s3 * 4 + q];
        f4add(acc0, v0); f4add(acc1, v1); f4add(acc0, v2); f4add(acc1, v3);
    }
    for (; j < e; ++j)
        f4add(acc0, pv[(size_t)srcs[j] * 4 + q]);
    f4add(acc0, acc1);
    ((float4*)s_acc)[node * 4 + q] = acc0;
    __syncthreads();

    const int gn = b * CNODES + tid;
    if (tid < CNODES && gn < NN) {
        const float4* fr = (const float4*)(feat + (size_t)gn * HID);
        const float4* sa = (const float4*)(s_acc + tid * 16);
        float t[HID];
        #pragma unroll
        for (int i2 = 0; i2 < 4; ++i2) {
            float4 f = fr[i2], a = sa[i2];
            t[i2*4+0] = fmaxf(f.x + a.x + s_b1[i2*4+0], 0.f);
            t[i2*4+1] = fmaxf(f.y + a.y + s_b1[i2*4+1], 0.f);
            t[i2*4+2] = fmaxf(f.z + a.z + s_b1[i2*4+2], 0.f);
            t[i2*4+3] = fmaxf(f.w + a.w + s_b1[i2*4+3], 0.f);
        }
        float h[HID];
        #pragma unroll
        for (int i2 = 0; i2 < HID; ++i2) {
            float acc = s_b2[i2];
            #pragma unroll
            for (int jj = 0; jj < HID; ++jj) acc += t[jj] * s_w2[i2 * HID + jj];
            h[i2] = fmaxf(acc, 0.f);
        }
        float o[HID];
        #pragma unroll
        for (int i2 = 0; i2 < HID; ++i2) {
            float acc = 0.f;
            #pragma unroll
            for (int jj = 0; jj < HID; ++jj) acc += h[jj] * s_w3[i2 * HID + jj];
            o[i2] = acc;
        }
        float4* po = (float4*)(outfeat + (size_t)gn * HID);
        #pragma unroll
        for (int i2 = 0; i2 < 4; ++i2)
            po[i2] = make_float4(o[i2*4+0], o[i2*4+1], o[i2*4+2], o[i2*4+3]);
    }
}

__global__ __launch_bounds__(256) void k_gagg2(
    const float* __restrict__ feat, const int* __restrict__ goff,
    const int* __restrict__ gsorted,
    const float* __restrict__ b1, const float* __restrict__ w2,
    const float* __restrict__ b2, const float* __restrict__ row,
    const float* __restrict__ rob,
    float* __restrict__ out)
{
    __shared__ float s_acc[CNODES * 16];
    __shared__ float s_w2[HID * HID], s_b1[HID], s_b2[HID], s_ro[HID];
    __shared__ int s_off[CNODES + 1];
    const int tid = threadIdx.x;
    const int b   = blockIdx.x;

    s_w2[tid] = w2[tid];
    if (tid < HID) { s_b1[tid] = b1[tid]; s_b2[tid] = b2[tid]; s_ro[tid] = row[tid]; }
    if (tid < CNODES + 1) s_off[tid] = goff[(size_t)b * 65 + tid];
    __syncthreads();

    const int node = tid >> 2, q = tid & 3;
    const int* srcs = gsorted + (size_t)b * NS;
    const float4* pv = (const float4*)feat;
    float4 acc0 = make_float4(0.f, 0.f, 0.f, 0.f);
    float4 acc1 = make_float4(0.f, 0.f, 0.f, 0.f);
    int j = s_off[node];
    const int e = s_off[node + 1];
    for (; j + 7 < e; j += 8) {
        int s0 = srcs[j],     s1 = srcs[j + 1], s2 = srcs[j + 2], s3 = srcs[j + 3];
        int s4 = srcs[j + 4], s5 = srcs[j + 5], s6 = srcs[j + 6], s7 = srcs[j + 7];
        float4 v0 = pv[(size_t)s0 * 4 + q];
        float4 v1 = pv[(size_t)s1 * 4 + q];
        float4 v2 = pv[(size_t)s2 * 4 + q];
        float4 v3 = pv[(size_t)s3 * 4 + q];
        float4 v4 = pv[(size_t)s4 * 4 + q];
        float4 v5 = pv[(size_t)s5 * 4 + q];
        float4 v6 = pv[(size_t)s6 * 4 + q];
        float4 v7 = pv[(size_t)s7 * 4 + q];
        f4add(acc0, v0); f4add(acc1, v1); f4add(acc0, v2); f4add(acc1, v3);
        f4add(acc0, v4); f4add(acc1, v5); f4add(acc0, v6); f4add(acc1, v7);
    }
    for (; j + 3 < e; j += 4) {
        int s0 = srcs[j], s1 = srcs[j + 1], s2 = srcs[j + 2], s3 = srcs[j + 3];
        float4 v0 = pv[(size_t)s0 * 4 + q];
        float4 v1 = pv[(size_t)s1 * 4 + q];
        float4 v2 = pv[(size_t)s2 * 4 + q];
        float4 v3 = pv[(size_t)s3 * 4 + q];
        f4add(acc0, v0); f4add(acc1, v1); f4add(acc0, v2); f4add(acc1, v3);
    }
    for (; j < e; ++j)
        f4add(acc0, pv[(size_t)srcs[j] * 4 + q]);
    f4add(acc0, acc1);
    ((float4*)s_acc)[node * 4 + q] = acc0;
    __syncthreads();

    const int gn = b * CNODES + tid;
    if (tid < CNODES && gn < NN) {
        const float4* fr = (const float4*)(feat + (size_t)gn * HID);
        const float4* sa = (const float4*)(s_acc + tid * 16);
        float t[HID];
        #pragma unroll
        for (int i2 = 0; i2 < 4; ++i2) {
            float4 f = fr[i2], a = sa[i2];
            t[i2*4+0] = fmaxf(f.x + a.x + s_b1[i2*4+0], 0.f);
            t[i2*4+1] = fmaxf(f.y + a.y + s_b1[i2*4+1], 0.f);
            t[i2*4+2] = fmaxf(f.z + a.z + s_b1[i2*4+2], 0.f);
            t[i2*4+3] = fmaxf(f.w + a.w + s_b1[i2*4+3], 0.f);
        }
        float res = rob[0];
        #pragma unroll
        for (int i2 = 0; i2 < HID; ++i2) {
            float acc = s_b2[i2];
            #pragma unroll
            for (int jj = 0; jj < HID; ++jj) acc += t[jj] * s_w2[i2 * HID + jj];
            res += acc * s_ro[i2];
        }
        out[gn] = res;
    }
}

// ===========================================================================
// FALLBACK PATH kernels (workspace too small): per-node embed + atomic scatter
// ===========================================================================
__global__ __launch_bounds__(256) void k_embed(
    const float* __restrict__ x,
    const float* __restrict__ conv_w, const float* __restrict__ conv_b,
    const float* __restrict__ fc_w,   const float* __restrict__ fc_b,
    const float* __restrict__ g1w1,
    float* __restrict__ p1)
{
    __shared__ float s_x[4][TL];
    __shared__ float s_h[4][FLAT + 3];
    __shared__ float s_e[4][EMB];

    const int w    = threadIdx.x >> 6;
    const int lane = threadIdx.x & 63;
    const int node = blockIdx.x * 4 + w;

    const float2* xr = (const float2*)(x + (size_t)node * TL);
    float2 v = xr[lane];
    s_x[w][lane * 2 + 0] = v.x;
    s_x[w][lane * 2 + 1] = v.y;
    __syncthreads();

    for (int o = lane; o < FLAT; o += 64) {
        int c = o / CL;
        int t = o - c * CL;
        float acc = conv_b[c];
        #pragma unroll
        for (int k = 0; k < KW; ++k)
            acc += s_x[w][t * ST + k] * conv_w[c * KW + k];
        s_h[w][o] = fmaxf(acc, 0.f);
    }
    __syncthreads();

    if (lane < EMB) {
        float acc = fc_b[lane];
        const float* wr = fc_w + lane * FLAT;
        for (int j = 0; j < FLAT; ++j)
            acc += s_h[w][j] * wr[j];
        s_e[w][lane] = acc;
    }
    __syncthreads();

    if (lane < HID) {
        float acc = 0.f;
        const float* wr = g1w1 + lane * EMB;
        #pragma unroll
        for (int j = 0; j < EMB; ++j)
            acc += s_e[w][j] * wr[j];
        p1[(size_t)node * HID + lane] = acc;
    }
}

__global__ __launch_bounds__(256) void k_scatter(
    const float* __restrict__ p, const int* __restrict__ ei,
    float* __restrict__ agg)
{
    long long t = (long long)blockIdx.x * 256 + threadIdx.x;
    int e = (int)(t >> 4);
    int k = (int)(t & 15);
    if (e >= NE) return;
    int src = ei[e];
    int dst = ei[NE + e];
    float v = p[(size_t)src * HID + k];
    atomicAdd(agg + (size_t)dst * HID + k, v);
}

__global__ __launch_bounds__(256) void k_mlp1(
    const float* __restrict__ p1, const float* __restrict__ agg,
    const float* __restrict__ b1, const float* __restrict__ w2,
    const float* __restrict__ b2, const float* __restrict__ w3,
    float* __restrict__ p2)
{
    __shared__ float s_w2[HID * HID], s_w3[HID * HID], s_b1[HID], s_b2[HID];
    int tid = threadIdx.x;
    s_w2[tid] = w2[tid];
    s_w3[tid] = w3[tid];
    if (tid < HID) { s_b1[tid] = b1[tid]; s_b2[tid] = b2[tid]; }
    __syncthreads();

    int n = blockIdx.x * 256 + tid;
    if (n >= NN) return;

    float t[HID], h[HID];
    const float4* pa = (const float4*)(p1  + (size_t)n * HID);
    const float4* pb = (const float4*)(agg + (size_t)n * HID);
    #pragma unroll
    for (int i = 0; i < 4; ++i) {
        float4 a = pa[i], b = pb[i];
        t[i*4+0] = fmaxf(a.x + b.x + s_b1[i*4+0], 0.f);
        t[i*4+1] = fmaxf(a.y + b.y + s_b1[i*4+1], 0.f);
        t[i*4+2] = fmaxf(a.z + b.z + s_b1[i*4+2], 0.f);
        t[i*4+3] = fmaxf(a.w + b.w + s_b1[i*4+3], 0.f);
    }
    #pragma unroll
    for (int i = 0; i < HID; ++i) {
        float acc = s_b2[i];
        #pragma unroll
        for (int j = 0; j < HID; ++j) acc += t[j] * s_w2[i * HID + j];
        h[i] = fmaxf(acc, 0.f);
    }
    float o[HID];
    #pragma unroll
    for (int i = 0; i < HID; ++i) {
        float acc = 0.f;
        #pragma unroll
        for (int j = 0; j < HID; ++j) acc += h[j] * s_w3[i * HID + j];
        o[i] = acc;
    }
    float4* po = (float4*)(p2 + (size_t)n * HID);
    #pragma unroll
    for (int i = 0; i < 4; ++i)
        po[i] = make_float4(o[i*4+0], o[i*4+1], o[i*4+2], o[i*4+3]);
}

__global__ __launch_bounds__(256) void k_final(
    const float* __restrict__ p2, const float* __restrict__ agg2,
    const float* __restrict__ b1, const float* __restrict__ w2,
    const float* __restrict__ b2, const float* __restrict__ row,
    const float* __restrict__ rob,
    float* __restrict__ out)
{
    __shared__ float s_w2[HID * HID], s_b1[HID], s_b2[HID], s_ro[HID];
    int tid = threadIdx.x;
    s_w2[tid] = w2[tid];
    if (tid < HID) { s_b1[tid] = b1[tid]; s_b2[tid] = b2[tid]; s_ro[tid] = row[tid]; }
    __syncthreads();

    int n = blockIdx.x * 256 + tid;
    if (n >= NN) return;

    float t[HID];
    const float4* pa = (const float4*)(p2   + (size_t)n * HID);
    const float4* pb = (const float4*)(agg2 + (size_t)n * HID);
    #pragma unroll
    for (int i = 0; i < 4; ++i) {
        float4 a = pa[i], b = pb[i];
        t[i*4+0] = fmaxf(a.x + b.x + s_b1[i*4+0], 0.f);
        t[i*4+1] = fmaxf(a.y + b.y + s_b1[i*4+1], 0.f);
        t[i*4+2] = fmaxf(a.z + b.z + s_b1[i*4+2], 0.f);
        t[i*4+3] = fmaxf(a.w + b.w + s_b1[i*4+3], 0.f);
    }
    float res = rob[0];
    #pragma unroll
    for (int i = 0; i < HID; ++i) {
        float acc = s_b2[i];
        #pragma unroll
        for (int j = 0; j < HID; ++j) acc += t[j] * s_w2[i * HID + j];
        res += acc * s_ro[i];
    }
    out[n] = res;
}

// ===========================================================================
extern "C" void kernel_launch(void* const* d_in, const int* in_sizes, int n_in,
                              void* d_out, int out_size, void* d_ws, size_t ws_size,
                              hipStream_t stream)
{
    const float* x      = (const float*)d_in[0];
    const int*   ei     = (const int*)  d_in[1];
    const float* conv_w = (const float*)d_in[2];
    const float* conv_b = (const float*)d_in[3];
    const float* fc_w   = (const float*)d_in[4];
    const float* fc_b   = (const float*)d_in[5];
    const float* g1w1   = (const float*)d_in[6];
    const float* g1b1   = (const float*)d_in[7];
    const float* g1w2   = (const float*)d_in[8];
    const float* g1b2   = (const float*)d_in[9];
    const float* g2w1   = (const float*)d_in[10];
    const float* g2b1   = (const float*)d_in[11];
    const float* g2w2   = (const float*)d_in[12];
    const float* g2b2   = (const float*)d_in[13];
    const float* ro_w   = (const float*)d_in[14];
    const float* ro_b   = (const float*)d_in[15];
    float* out = (float*)d_out;

    // workspace layout:
    //   A       [NN*HID] f32        p1 (projected features)
    //   B       [NN*HID] f32        p2 (layer-2 projected features)
    //   wcTj    [JPAD*HID] f32      combined fc+g1w1 weight, j-major
    //   bc      [16] f32            combined bias
    //   gcur    [BBUCK] i32         bin cursors
    //   gbin    [BBUCK*NPB] u32     packed (local_dst<<17)|src per bin bucket
    //   goff    [NGB*65] i32        per-node offsets within gagg bucket
    //   gsorted [NGB*NS] i32        dst-sorted src ids per gagg bucket
    float* A    = (float*)d_ws;
    float* B    = A + (size_t)NN * HID;
    float* wcTj = B + (size_t)NN * HID;
    float* bc   = wcTj + (size_t)JPAD * HID;
    int*   gcur = (int*)(bc + 16);
    unsigned int* gbin = (unsigned int*)(gcur + BBUCK);
    int*   goff    = (int*)(gbin + (size_t)BBUCK * NPB);
    int*   gsorted = goff + (size_t)NGB * 65;
    const size_t need = (size_t)((char*)(gsorted + (size_t)NGB * NS) - (char*)d_ws);

    if (ws_size >= need) {
        k_prep<<<1, 256, 0, stream>>>(g1w1, fc_w, fc_b, wcTj, bc, gcur);
        k_convfc<<<NN / 32, 256, 0, stream>>>(x, conv_w, conv_b, wcTj, bc, A);
        k_bin<<<NBIN, 256, 0, stream>>>(ei, gcur, gbin);
        k_sort<<<NGB, 256, 0, stream>>>(gbin, gcur, goff, gsorted);
        // GIN layer 1: atomic-free gather + MLP + layer-2 projection
        k_gagg1<<<NGB, 256, 0, stream>>>(A, goff, gsorted, g1b1, g1w2, g1b2,
                                         g2w1, B);
        // GIN layer 2: atomic-free gather + MLP + readout
        k_gagg2<<<NGB, 256, 0, stream>>>(B, goff, gsorted, g2b1, g2w2, g2b2,
                                         ro_w, ro_b, out);
    } else {
        // --- fallback: fused per-node embed + atomic scatter ---
        k_embed<<<NN / 4, 256, 0, stream>>>(x, conv_w, conv_b, fc_w, fc_b,
                                            g1w1, A);
        hipMemsetAsync(B, 0, (size_t)NN * HID * sizeof(float), stream);
        k_scatter<<<(int)(((long long)NE * HID) / 256), 256, 0, stream>>>(A, ei, B);
        k_mlp1<<<(NN + 255) / 256, 256, 0, stream>>>(A, B, g1b1, g1w2, g1b2,
                                                     g2w1, A);
        hipMemsetAsync(B, 0, (size_t)NN * HID * sizeof(float), stream);
        k_scatter<<<(int)(((long long)NE * HID) / 256), 256, 0, stream>>>(A, ei, B);
        k_final<<<(NN + 255) / 256, 256, 0, stream>>>(A, B, g2b1, g2w2, g2b2,
                                                      ro_w, ro_b, out);
    }
}

// Round 11
// 363.683 us; speedup vs baseline: 1.1086x; 1.1086x over previous
//
#include <hip/hip_runtime.h>

#define NN   100000
#define TL   128
#define OC   5
#define KW   7
#define ST   3
#define CL   41          // (128-7)/3+1
#define FLAT 205         // 5*41
#define EMB  32
#define HID  16
#define NE   3200000

#define CLP  44                  // per-channel padded conv length (4-aligned)
#define JP   220                 // OC*CLP, padded flat length
#define JB   55                  // JP/4 float4 blocks
#define WN   8                   // convfc nodes per WAVE (4 waves -> 32/block)
#define SXW  1048                // per-wave s_x slice (8*129=1032, +16 over-read pad)
#define NCVB 3125                // conv-role blocks (NN/32)

#define BBUCK  391               // bin buckets (256 nodes each, dst>>8)
#define NPB    14336             // slots per bin bucket (mean fill ~12980, +16 sigma)
#define TILE   4096              // edges per bin-role block
#define NBIN   782               // ceil(NE/TILE)
#define CVBG   3910              // fused grid: 5*782 (4 conv : 1 bin interleave)
#define CNODES 64                // nodes per gagg/sort bucket
#define NGB    1563              // ceil(NN/64)
#define NS     2560              // sorted-src capacity per 64-node bucket (mean 2048)
#define SENT   0xFFFFFFFFu       // sentinel slot (real words are < 2^26)

#define SMEMF  11232             // union LDS floats: conv 4*SXW+4*WN*JP=11232 > bin 5525

__device__ __forceinline__ void f4add(float4& a, const float4 v) {
    a.x += v.x; a.y += v.y; a.z += v.z; a.w += v.w;
}

// ===========================================================================
// Precompute combined weight wcTl = g1w1 @ fc_w, L-MAJOR and channel-padded:
// wcTl[l*JP + c*CLP + t] = sum_m g1w1[l,m]*fc_w[m, c*41+t]  (t<41; else 0).
// bc = g1w1 @ fc_b.  Also init per-bucket bin cursors gcur[b] = b*NPB.
// ===========================================================================
__global__ __launch_bounds__(256) void k_prep(
    const float* __restrict__ g1w1, const float* __restrict__ fc_w,
    const float* __restrict__ fc_b,
    float* __restrict__ wcTl, float* __restrict__ bc,
    int* __restrict__ gcur)
{
    int tid = threadIdx.x;
    for (int idx = tid; idx < HID * JP; idx += 256) {
        int l  = idx / JP;
        int jp = idx - l * JP;
        int c  = jp / CLP;
        int t  = jp - c * CLP;
        float s = 0.f;
        if (t < CL) {
            int j = c * CL + t;
            #pragma unroll
            for (int m = 0; m < EMB; ++m)
                s = fmaf(g1w1[l * EMB + m], fc_w[m * FLAT + j], s);
        }
        wcTl[idx] = s;
    }
    if (tid < HID) {
        float s = 0.f;
        #pragma unroll
        for (int m = 0; m < EMB; ++m)
            s = fmaf(g1w1[tid * EMB + m], fc_b[m], s);
        bc[tid] = s;
    }
    for (int b = tid; b < BBUCK; b += 256)
        gcur[b] = b * NPB;
}

// ===========================================================================
// FUSED convfc + bin, heterogeneous block roles (4:1 interleave).
// r6-r10 post-mortem: convfc floor is ~68us across 5 structures (DS-count,
// occupancy, barriers, register-h all refuted; high-occupancy variants are
// SLOWER).  The remaining lever is overlap: convfc (latency-bound, r9
// wave-sync body) and bin (memory-phase-bound, r6 body) are data-independent
// but serialized on the stream (~70+55us).  One kernel, every 5th block is a
// bin block -> both roles co-resident on each CU; conv stalls filled by bin
// work.  LDS: single 44.9KB buffer aliased per role (bin needs 21.6KB).
// ===========================================================================
__global__ __launch_bounds__(256) void k_convbin(
    const float* __restrict__ x,
    const float* __restrict__ conv_w, const float* __restrict__ conv_b,
    const float* __restrict__ wcTl,  const float* __restrict__ bc,
    float* __restrict__ p1,
    const int* __restrict__ ei, int* __restrict__ gcur,
    unsigned int* __restrict__ gbin)
{
    __shared__ float smem[SMEMF];
    const int bid = blockIdx.x;
    const int grp = bid / 5, pos = bid - grp * 5;
    const int tid = threadIdx.x;

    if (pos == 4) {
        // ------------------- BIN ROLE (block grp of 782) -------------------
        unsigned int* s_stage = (unsigned int*)smem;          // TILE words
        int* s_cnt  = (int*)smem + TILE;
        int* s_ofs  = s_cnt  + BBUCK;
        int* s_base = s_ofs  + BBUCK;
        int* s_sum  = s_base + BBUCK;                         // 256 words

        const int e0   = grp * TILE;
        const int cntE = min(TILE, NE - e0);

        for (int b = tid; b < BBUCK; b += 256) s_cnt[b] = 0;
        __syncthreads();

        // P1: histogram over 391 buckets
        for (int i = tid; i < cntE; i += 256)
            atomicAdd(&s_cnt[ei[NE + e0 + i] >> 8], 1);
        __syncthreads();

        // P2a: aligned global reservation (one atomic per nonempty bucket)
        for (int b = tid; b < BBUCK; b += 256) {
            int c = s_cnt[b];
            s_base[b] = c ? atomicAdd(&gcur[b], (c + 15) & ~15) : 0;
        }

        // P2b: exclusive scan of s_cnt -> s_ofs (chunks of 2)
        int v0 = 0, v1 = 0;
        {
            int i0 = tid * 2;
            if (i0     < BBUCK) v0 = s_cnt[i0];
            if (i0 + 1 < BBUCK) v1 = s_cnt[i0 + 1];
        }
        int csum = v0 + v1;
        s_sum[tid] = csum;
        __syncthreads();
        #pragma unroll
        for (int d = 1; d < 256; d <<= 1) {
            int t = (tid >= d) ? s_sum[tid - d] : 0;
            __syncthreads();
            s_sum[tid] += t;
            __syncthreads();
        }
        {
            int run = s_sum[tid] - csum;
            int i0 = tid * 2;
            if (i0     < BBUCK) { s_ofs[i0]     = run; run += v0; }
            if (i0 + 1 < BBUCK) { s_ofs[i0 + 1] = run; }
        }
        __syncthreads();

        // P3: scatter packed (local_dst<<17)|src into LDS staging
        for (int i = tid; i < cntE; i += 256) {
            int s = ei[e0 + i];
            int d = ei[NE + e0 + i];
            int b = d >> 8;
            int pp = atomicAdd(&s_ofs[b], 1);
            s_stage[pp] = ((unsigned int)(d & 255) << 17) | (unsigned int)s;
        }
        __syncthreads();

        // P4: coalesced copy-out, sentinel-padded to aligned reservation
        const int wid = tid >> 6, lane = tid & 63;
        for (int b = wid; b < BBUCK; b += 4) {
            int cnt = s_cnt[b];
            if (!cnt) continue;
            int res = (cnt + 15) & ~15;
            int rdo = s_ofs[b] - cnt;
            int gb  = s_base[b];
            int lim = min(res, b * NPB + NPB - gb);   // overflow clamp
            for (int j = lane; j < lim; j += 64)
                gbin[(size_t)gb + j] = (j < cnt) ? s_stage[rdo + j] : SENT;
        }
        return;
    }

    // ------------------- CONV ROLE (r9 wave-sync body, verified) -----------
    const int cb = grp * 4 + pos;
    if (cb >= NCVB) return;

    float* s_x  = smem;
    float* s_h2 = smem + 4 * SXW;
    const int wv   = tid >> 6;
    const int lane = tid & 63;
    const long long nw = (long long)cb * 32 + wv * WN;   // NN = 32*3125

    float* sx = s_x  + wv * SXW;
    float* sh = s_h2 + wv * (WN * JP);

    // stage this wave's 8 x-rows: 256 float4 coalesced, row-padded writes
    const float4* xv = (const float4*)(x + nw * TL);
    #pragma unroll
    for (int c = 0; c < 4; ++c) {
        int f4  = c * 64 + lane;      // 0..255
        int row = f4 >> 5;            // 0..7
        int c4  = f4 & 31;
        float4 v = xv[f4];
        float* d = sx + row * 129 + c4 * 4;
        d[0] = v.x; d[1] = v.y; d[2] = v.z; d[3] = v.w;
    }
    // wave-local phase fence: all LDS writes retired before cross-lane reads
    asm volatile("s_waitcnt lgkmcnt(0)" ::: "memory");

    // conv: 55 (c,tg) groups x 8 nodes = 440 items, ~6.9 per lane
    for (int i = lane; i < 55 * WN; i += 64) {
        int n  = i & (WN - 1);
        int ci = i >> 3;              // 0..54
        int c  = ci / 11;
        int tg = ci - c * 11;
        int t0 = tg * 4;
        const float* xr = sx + n * 129 + t0 * ST;
        float xx[16];
        #pragma unroll
        for (int k = 0; k < 16; ++k) xx[k] = xr[k];
        const float* wr = conv_w + c * KW;
        float w0 = wr[0], w1 = wr[1], w2 = wr[2], w3 = wr[3],
              w4 = wr[4], w5 = wr[5], w6 = wr[6];
        float bb = conv_b[c];
        float4 r;
        r.x = fmaxf(bb + xx[0]*w0 + xx[1]*w1 + xx[2]*w2 + xx[3]*w3
                       + xx[4]*w4 + xx[5]*w5 + xx[6]*w6, 0.f);
        r.y = (t0 + 1 < CL)
            ? fmaxf(bb + xx[3]*w0 + xx[4]*w1 + xx[5]*w2 + xx[6]*w3
                       + xx[7]*w4 + xx[8]*w5 + xx[9]*w6, 0.f) : 0.f;
        r.z = (t0 + 2 < CL)
            ? fmaxf(bb + xx[6]*w0 + xx[7]*w1 + xx[8]*w2 + xx[9]*w3
                       + xx[10]*w4 + xx[11]*w5 + xx[12]*w6, 0.f) : 0.f;
        r.w = (t0 + 3 < CL)
            ? fmaxf(bb + xx[9]*w0 + xx[10]*w1 + xx[11]*w2 + xx[12]*w3
                       + xx[13]*w4 + xx[14]*w5 + xx[15]*w6, 0.f) : 0.f;
        *(float4*)(sh + n * JP + c * CLP + t0) = r;   // 16B-aligned b128
    }
    // wave-local phase fence before FC's cross-lane h reads
    asm volatile("s_waitcnt lgkmcnt(0)" ::: "memory");

    // FC: lane = (l, g); handles nodes g and g+4 (weight row reused 2x).
    const int l = lane & 15;
    const int g = lane >> 4;          // 0..3
    float a0 = bc[l];
    float a1 = a0;
    const float4* wl = (const float4*)(wcTl + l * JP);
    const float4* h0 = (const float4*)(sh + g * JP);
    const float4* h1 = (const float4*)(sh + (g + 4) * JP);
    #pragma unroll 5
    for (int jb = 0; jb < JB; ++jb) {
        float4 w = wl[jb];
        float4 p = h0[jb];
        float4 q = h1[jb];
        a0 = fmaf(p.x, w.x, fmaf(p.y, w.y, fmaf(p.z, w.z, fmaf(p.w, w.w, a0))));
        a1 = fmaf(q.x, w.x, fmaf(q.y, w.y, fmaf(q.z, w.z, fmaf(q.w, w.w, a1))));
    }
    p1[(nw + g)     * HID + l] = a0;
    p1[(nw + g + 4) * HID + l] = a1;
}

// ===========================================================================
// Quarter-bucket counting sort v2 (unchanged, verified r6).
// ===========================================================================
__global__ __launch_bounds__(256) void k_sort(
    const unsigned int* __restrict__ gbin, const int* __restrict__ gcur,
    int* __restrict__ goff, int* __restrict__ gsorted)
{
    __shared__ unsigned int s_m[NS];                 // 10 KB
    __shared__ int s_cnt[CNODES], s_ofs[CNODES], s_loc[CNODES];
    __shared__ int s_n;
    const int tid = threadIdx.x;
    const int b64 = blockIdx.x;
    const int bkt = b64 >> 2, q = b64 & 3;
    const int nslots = min(gcur[bkt] - bkt * NPB, NPB);
    const unsigned int* run = gbin + (size_t)bkt * NPB;

    if (tid < CNODES) s_cnt[tid] = 0;
    if (tid == 0) s_n = 0;
    __syncthreads();

    // filtered append + histogram in one pass
    for (int i = tid; i < nslots; i += 256) {
        unsigned int w = run[i];
        if (w != SENT && (int)(w >> 23) == q) {
            int p = atomicAdd(&s_n, 1);
            if (p < NS) {                            // clamp (never hits)
                s_m[p] = w;
                atomicAdd(&s_cnt[(w >> 17) & 63], 1);
            }
        }
    }
    __syncthreads();

    // inclusive Hillis-Steele scan over 64 counters
    if (tid < CNODES) s_ofs[tid] = s_cnt[tid];
    __syncthreads();
    #pragma unroll
    for (int d = 1; d < CNODES; d <<= 1) {
        int t = (tid < CNODES && tid >= d) ? s_ofs[tid - d] : 0;
        __syncthreads();
        if (tid < CNODES) s_ofs[tid] += t;
        __syncthreads();
    }
    if (tid < CNODES) {
        int inc = s_ofs[tid];
        s_loc[tid] = inc - s_cnt[tid];               // exclusive
        goff[(size_t)b64 * 65 + tid + 1] = inc;
    }
    if (tid == 0) goff[(size_t)b64 * 65] = 0;
    __syncthreads();

    // scatter srcs into block-exclusive sorted region
    const int n = min(s_n, NS);
    int* dst = gsorted + (size_t)b64 * NS;
    for (int i = tid; i < n; i += 256) {
        unsigned int w = s_m[i];
        int pos = atomicAdd(&s_loc[(w >> 17) & 63], 1);
        dst[pos] = (int)(w & 0x1FFFFu);
    }
}

// ===========================================================================
// Fused gather-aggregate + GIN MLP, ATOMIC-FREE (unchanged, verified r6).
// ===========================================================================
__global__ __launch_bounds__(256) void k_gagg1(
    const float* __restrict__ feat, const int* __restrict__ goff,
    const int* __restrict__ gsorted,
    const float* __restrict__ b1, const float* __restrict__ w2,
    const float* __restrict__ b2, const float* __restrict__ w3,
    float* __restrict__ outfeat)
{
    __shared__ float s_acc[CNODES * 16];
    __shared__ float s_w2[HID * HID], s_w3[HID * HID], s_b1[HID], s_b2[HID];
    __shared__ int s_off[CNODES + 1];
    const int tid = threadIdx.x;
    const int b   = blockIdx.x;

    s_w2[tid] = w2[tid];
    s_w3[tid] = w3[tid];
    if (tid < HID) { s_b1[tid] = b1[tid]; s_b2[tid] = b2[tid]; }
    if (tid < CNODES + 1) s_off[tid] = goff[(size_t)b * 65 + tid];
    __syncthreads();

    const int node = tid >> 2, q = tid & 3;
    const int* srcs = gsorted + (size_t)b * NS;
    const float4* pv = (const float4*)feat;
    float4 acc0 = make_float4(0.f, 0.f, 0.f, 0.f);
    float4 acc1 = make_float4(0.f, 0.f, 0.f, 0.f);
    int j = s_off[node];
    const int e = s_off[node + 1];
    for (; j + 7 < e; j += 8) {
        int s0 = srcs[j],     s1 = srcs[j + 1], s2 = srcs[j + 2], s3 = srcs[j + 3];
        int s4 = srcs[j + 4], s5 = srcs[j + 5], s6 = srcs[j + 6], s7 = srcs[j + 7];
        float4 v0 = pv[(size_t)s0 * 4 + q];
        float4 v1 = pv[(size_t)s1 * 4 + q];
        float4 v2 = pv[(size_t)s2 * 4 + q];
        float4 v3 = pv[(size_t)s3 * 4 + q];
        float4 v4 = pv[(size_t)s4 * 4 + q];
        float4 v5 = pv[(size_t)s5 * 4 + q];
        float4 v6 = pv[(size_t)s6 * 4 + q];
        float4 v7 = pv[(size_t)s7 * 4 + q];
        f4add(acc0, v0); f4add(acc1, v1); f4add(acc0, v2); f4add(acc1, v3);
        f4add(acc0, v4); f4add(acc1, v5); f4add(acc0, v6); f4add(acc1, v7);
    }
    for (; j + 3 < e; j += 4) {
        int s0 = srcs[j], s1 = srcs[j + 1], s2 = srcs[j + 2], s3 = srcs[j + 3];
        float4 v0 = pv[(size_t)s0 * 4 + q];
        float4 v1 = pv[(size_t)s1 * 4 + q];
        float4 v2 = pv[(size_t)s2 * 4 + q];
        float4 v3 = pv[(size_t)s3 * 4 + q];
        f4add(acc0, v0); f4add(acc1, v1); f4add(acc0, v2); f4add(acc1, v3);
    }
    for (; j < e; ++j)
        f4add(acc0, pv[(size_t)srcs[j] * 4 + q]);
    f4add(acc0, acc1);
    ((float4*)s_acc)[node * 4 + q] = acc0;
    __syncthreads();

    const int gn = b * CNODES + tid;
    if (tid < CNODES && gn < NN) {
        const float4* fr = (const float4*)(feat + (size_t)gn * HID);
        const float4* sa = (const float4*)(s_acc + tid * 16);
        float t[HID];
        #pragma unroll
        for (int i2 = 0; i2 < 4; ++i2) {
            float4 f = fr[i2], a = sa[i2];
            t[i2*4+0] = fmaxf(f.x + a.x + s_b1[i2*4+0], 0.f);
            t[i2*4+1] = fmaxf(f.y + a.y + s_b1[i2*4+1], 0.f);
            t[i2*4+2] = fmaxf(f.z + a.z + s_b1[i2*4+2], 0.f);
            t[i2*4+3] = fmaxf(f.w + a.w + s_b1[i2*4+3], 0.f);
        }
        float h[HID];
        #pragma unroll
        for (int i2 = 0; i2 < HID; ++i2) {
            float acc = s_b2[i2];
            #pragma unroll
            for (int jj = 0; jj < HID; ++jj) acc += t[jj] * s_w2[i2 * HID + jj];
            h[i2] = fmaxf(acc, 0.f);
        }
        float o[HID];
        #pragma unroll
        for (int i2 = 0; i2 < HID; ++i2) {
            float acc = 0.f;
            #pragma unroll
            for (int jj = 0; jj < HID; ++jj) acc += h[jj] * s_w3[i2 * HID + jj];
            o[i2] = acc;
        }
        float4* po = (float4*)(outfeat + (size_t)gn * HID);
        #pragma unroll
        for (int i2 = 0; i2 < 4; ++i2)
            po[i2] = make_float4(o[i2*4+0], o[i2*4+1], o[i2*4+2], o[i2*4+3]);
    }
}

__global__ __launch_bounds__(256) void k_gagg2(
    const float* __restrict__ feat, const int* __restrict__ goff,
    const int* __restrict__ gsorted,
    const float* __restrict__ b1, const float* __restrict__ w2,
    const float* __restrict__ b2, const float* __restrict__ row,
    const float* __restrict__ rob,
    float* __restrict__ out)
{
    __shared__ float s_acc[CNODES * 16];
    __shared__ float s_w2[HID * HID], s_b1[HID], s_b2[HID], s_ro[HID];
    __shared__ int s_off[CNODES + 1];
    const int tid = threadIdx.x;
    const int b   = blockIdx.x;

    s_w2[tid] = w2[tid];
    if (tid < HID) { s_b1[tid] = b1[tid]; s_b2[tid] = b2[tid]; s_ro[tid] = row[tid]; }
    if (tid < CNODES + 1) s_off[tid] = goff[(size_t)b * 65 + tid];
    __syncthreads();

    const int node = tid >> 2, q = tid & 3;
    const int* srcs = gsorted + (size_t)b * NS;
    const float4* pv = (const float4*)feat;
    float4 acc0 = make_float4(0.f, 0.f, 0.f, 0.f);
    float4 acc1 = make_float4(0.f, 0.f, 0.f, 0.f);
    int j = s_off[node];
    const int e = s_off[node + 1];
    for (; j + 7 < e; j += 8) {
        int s0 = srcs[j],     s1 = srcs[j + 1], s2 = srcs[j + 2], s3 = srcs[j + 3];
        int s4 = srcs[j + 4], s5 = srcs[j + 5], s6 = srcs[j + 6], s7 = srcs[j + 7];
        float4 v0 = pv[(size_t)s0 * 4 + q];
        float4 v1 = pv[(size_t)s1 * 4 + q];
        float4 v2 = pv[(size_t)s2 * 4 + q];
        float4 v3 = pv[(size_t)s3 * 4 + q];
        float4 v4 = pv[(size_t)s4 * 4 + q];
        float4 v5 = pv[(size_t)s5 * 4 + q];
        float4 v6 = pv[(size_t)s6 * 4 + q];
        float4 v7 = pv[(size_t)s7 * 4 + q];
        f4add(acc0, v0); f4add(acc1, v1); f4add(acc0, v2); f4add(acc1, v3);
        f4add(acc0, v4); f4add(acc1, v5); f4add(acc0, v6); f4add(acc1, v7);
    }
    for (; j + 3 < e; j += 4) {
        int s0 = srcs[j], s1 = srcs[j + 1], s2 = srcs[j + 2], s3 = srcs[j + 3];
        float4 v0 = pv[(size_t)s0 * 4 + q];
        float4 v1 = pv[(size_t)s1 * 4 + q];
        float4 v2 = pv[(size_t)s2 * 4 + q];
        float4 v3 = pv[(size_t)s3 * 4 + q];
        f4add(acc0, v0); f4add(acc1, v1); f4add(acc0, v2); f4add(acc1, v3);
    }
    for (; j < e; ++j)
        f4add(acc0, pv[(size_t)srcs[j] * 4 + q]);
    f4add(acc0, acc1);
    ((float4*)s_acc)[node * 4 + q] = acc0;
    __syncthreads();

    const int gn = b * CNODES + tid;
    if (tid < CNODES && gn < NN) {
        const float4* fr = (const float4*)(feat + (size_t)gn * HID);
        const float4* sa = (const float4*)(s_acc + tid * 16);
        float t[HID];
        #pragma unroll
        for (int i2 = 0; i2 < 4; ++i2) {
            float4 f = fr[i2], a = sa[i2];
            t[i2*4+0] = fmaxf(f.x + a.x + s_b1[i2*4+0], 0.f);
            t[i2*4+1] = fmaxf(f.y + a.y + s_b1[i2*4+1], 0.f);
            t[i2*4+2] = fmaxf(f.z + a.z + s_b1[i2*4+2], 0.f);
            t[i2*4+3] = fmaxf(f.w + a.w + s_b1[i2*4+3], 0.f);
        }
        float res = rob[0];
        #pragma unroll
        for (int i2 = 0; i2 < HID; ++i2) {
            float acc = s_b2[i2];
            #pragma unroll
            for (int jj = 0; jj < HID; ++jj) acc += t[jj] * s_w2[i2 * HID + jj];
            res += acc * s_ro[i2];
        }
        out[gn] = res;
    }
}

// ===========================================================================
// FALLBACK PATH kernels (workspace too small): per-node embed + atomic scatter
// ===========================================================================
__global__ __launch_bounds__(256) void k_embed(
    const float* __restrict__ x,
    const float* __restrict__ conv_w, const float* __restrict__ conv_b,
    const float* __restrict__ fc_w,   const float* __restrict__ fc_b,
    const float* __restrict__ g1w1,
    float* __restrict__ p1)
{
    __shared__ float s_x[4][TL];
    __shared__ float s_h[4][FLAT + 3];
    __shared__ float s_e[4][EMB];

    const int w    = threadIdx.x >> 6;
    const int lane = threadIdx.x & 63;
    const int node = blockIdx.x * 4 + w;

    const float2* xr = (const float2*)(x + (size_t)node * TL);
    float2 v = xr[lane];
    s_x[w][lane * 2 + 0] = v.x;
    s_x[w][lane * 2 + 1] = v.y;
    __syncthreads();

    for (int o = lane; o < FLAT; o += 64) {
        int c = o / CL;
        int t = o - c * CL;
        float acc = conv_b[c];
        #pragma unroll
        for (int k = 0; k < KW; ++k)
            acc += s_x[w][t * ST + k] * conv_w[c * KW + k];
        s_h[w][o] = fmaxf(acc, 0.f);
    }
    __syncthreads();

    if (lane < EMB) {
        float acc = fc_b[lane];
        const float* wr = fc_w + lane * FLAT;
        for (int j = 0; j < FLAT; ++j)
            acc += s_h[w][j] * wr[j];
        s_e[w][lane] = acc;
    }
    __syncthreads();

    if (lane < HID) {
        float acc = 0.f;
        const float* wr = g1w1 + lane * EMB;
        #pragma unroll
        for (int j = 0; j < EMB; ++j)
            acc += s_e[w][j] * wr[j];
        p1[(size_t)node * HID + lane] = acc;
    }
}

__global__ __launch_bounds__(256) void k_scatter(
    const float* __restrict__ p, const int* __restrict__ ei,
    float* __restrict__ agg)
{
    long long t = (long long)blockIdx.x * 256 + threadIdx.x;
    int e = (int)(t >> 4);
    int k = (int)(t & 15);
    if (e >= NE) return;
    int src = ei[e];
    int dst = ei[NE + e];
    float v = p[(size_t)src * HID + k];
    atomicAdd(agg + (size_t)dst * HID + k, v);
}

__global__ __launch_bounds__(256) void k_mlp1(
    const float* __restrict__ p1, const float* __restrict__ agg,
    const float* __restrict__ b1, const float* __restrict__ w2,
    const float* __restrict__ b2, const float* __restrict__ w3,
    float* __restrict__ p2)
{
    __shared__ float s_w2[HID * HID], s_w3[HID * HID], s_b1[HID], s_b2[HID];
    int tid = threadIdx.x;
    s_w2[tid] = w2[tid];
    s_w3[tid] = w3[tid];
    if (tid < HID) { s_b1[tid] = b1[tid]; s_b2[tid] = b2[tid]; }
    __syncthreads();

    int n = blockIdx.x * 256 + tid;
    if (n >= NN) return;

    float t[HID], h[HID];
    const float4* pa = (const float4*)(p1  + (size_t)n * HID);
    const float4* pb = (const float4*)(agg + (size_t)n * HID);
    #pragma unroll
    for (int i = 0; i < 4; ++i) {
        float4 a = pa[i], b = pb[i];
        t[i*4+0] = fmaxf(a.x + b.x + s_b1[i*4+0], 0.f);
        t[i*4+1] = fmaxf(a.y + b.y + s_b1[i*4+1], 0.f);
        t[i*4+2] = fmaxf(a.z + b.z + s_b1[i*4+2], 0.f);
        t[i*4+3] = fmaxf(a.w + b.w + s_b1[i*4+3], 0.f);
    }
    #pragma unroll
    for (int i = 0; i < HID; ++i) {
        float acc = s_b2[i];
        #pragma unroll
        for (int j = 0; j < HID; ++j) acc += t[j] * s_w2[i * HID + j];
        h[i] = fmaxf(acc, 0.f);
    }
    float o[HID];
    #pragma unroll
    for (int i = 0; i < HID; ++i) {
        float acc = 0.f;
        #pragma unroll
        for (int j = 0; j < HID; ++j) acc += h[j] * s_w3[i * HID + j];
        o[i] = acc;
    }
    float4* po = (float4*)(p2 + (size_t)n * HID);
    #pragma unroll
    for (int i = 0; i < 4; ++i)
        po[i] = make_float4(o[i*4+0], o[i*4+1], o[i*4+2], o[i*4+3]);
}

__global__ __launch_bounds__(256) void k_final(
    const float* __restrict__ p2, const float* __restrict__ agg2,
    const float* __restrict__ b1, const float* __restrict__ w2,
    const float* __restrict__ b2, const float* __restrict__ row,
    const float* __restrict__ rob,
    float* __restrict__ out)
{
    __shared__ float s_w2[HID * HID], s_b1[HID], s_b2[HID], s_ro[HID];
    int tid = threadIdx.x;
    s_w2[tid] = w2[tid];
    if (tid < HID) { s_b1[tid] = b1[tid]; s_b2[tid] = b2[tid]; s_ro[tid] = row[tid]; }
    __syncthreads();

    int n = blockIdx.x * 256 + tid;
    if (n >= NN) return;

    float t[HID];
    const float4* pa = (const float4*)(p2   + (size_t)n * HID);
    const float4* pb = (const float4*)(agg2 + (size_t)n * HID);
    #pragma unroll
    for (int i = 0; i < 4; ++i) {
        float4 a = pa[i], b = pb[i];
        t[i*4+0] = fmaxf(a.x + b.x + s_b1[i*4+0], 0.f);
        t[i*4+1] = fmaxf(a.y + b.y + s_b1[i*4+1], 0.f);
        t[i*4+2] = fmaxf(a.z + b.z + s_b1[i*4+2], 0.f);
        t[i*4+3] = fmaxf(a.w + b.w + s_b1[i*4+3], 0.f);
    }
    float res = rob[0];
    #pragma unroll
    for (int i = 0; i < HID; ++i) {
        float acc = s_b2[i];
        #pragma unroll
        for (int j = 0; j < HID; ++j) acc += t[j] * s_w2[i * HID + j];
        res += acc * s_ro[i];
    }
    out[n] = res;
}

// ===========================================================================
extern "C" void kernel_launch(void* const* d_in, const int* in_sizes, int n_in,
                              void* d_out, int out_size, void* d_ws, size_t ws_size,
                              hipStream_t stream)
{
    const float* x      = (const float*)d_in[0];
    const int*   ei     = (const int*)  d_in[1];
    const float* conv_w = (const float*)d_in[2];
    const float* conv_b = (const float*)d_in[3];
    const float* fc_w   = (const float*)d_in[4];
    const float* fc_b   = (const float*)d_in[5];
    const float* g1w1   = (const float*)d_in[6];
    const float* g1b1   = (const float*)d_in[7];
    const float* g1w2   = (const float*)d_in[8];
    const float* g1b2   = (const float*)d_in[9];
    const float* g2w1   = (const float*)d_in[10];
    const float* g2b1   = (const float*)d_in[11];
    const float* g2w2   = (const float*)d_in[12];
    const float* g2b2   = (const float*)d_in[13];
    const float* ro_w   = (const float*)d_in[14];
    const float* ro_b   = (const float*)d_in[15];
    float* out = (float*)d_out;

    // workspace layout:
    //   A       [NN*HID] f32        p1 (projected features)
    //   B       [NN*HID] f32        p2 (layer-2 projected features)
    //   wcTl    [HID*JP] f32        combined fc+g1w1 weight, l-major padded
    //   bc      [16] f32            combined bias
    //   gcur    [BBUCK] i32         bin cursors
    //   gbin    [BBUCK*NPB] u32     packed (local_dst<<17)|src per bin bucket
    //   goff    [NGB*65] i32        per-node offsets within gagg bucket
    //   gsorted [NGB*NS] i32        dst-sorted src ids per gagg bucket
    float* A    = (float*)d_ws;
    float* B    = A + (size_t)NN * HID;
    float* wcTl = B + (size_t)NN * HID;
    float* bc   = wcTl + (size_t)HID * JP;
    int*   gcur = (int*)(bc + 16);
    unsigned int* gbin = (unsigned int*)(gcur + BBUCK);
    int*   goff    = (int*)(gbin + (size_t)BBUCK * NPB);
    int*   gsorted = goff + (size_t)NGB * 65;
    const size_t need = (size_t)((char*)(gsorted + (size_t)NGB * NS) - (char*)d_ws);

    if (ws_size >= need) {
        k_prep<<<1, 256, 0, stream>>>(g1w1, fc_w, fc_b, wcTl, bc, gcur);
        // fused: convfc (r9 body) overlapped with bin (r6 body), 4:1 interleave
        k_convbin<<<CVBG, 256, 0, stream>>>(x, conv_w, conv_b, wcTl, bc, A,
                                            ei, gcur, gbin);
        k_sort<<<NGB, 256, 0, stream>>>(gbin, gcur, goff, gsorted);
        // GIN layer 1: atomic-free gather + MLP + layer-2 projection
        k_gagg1<<<NGB, 256, 0, stream>>>(A, goff, gsorted, g1b1, g1w2, g1b2,
                                         g2w1, B);
        // GIN layer 2: atomic-free gather + MLP + readout
        k_gagg2<<<NGB, 256, 0, stream>>>(B, goff, gsorted, g2b1, g2w2, g2b2,
                                         ro_w, ro_b, out);
    } else {
        // --- fallback: fused per-node embed + atomic scatter ---
        k_embed<<<NN / 4, 256, 0, stream>>>(x, conv_w, conv_b, fc_w, fc_b,
                                            g1w1, A);
        hipMemsetAsync(B, 0, (size_t)NN * HID * sizeof(float), stream);
        k_scatter<<<(int)(((long long)NE * HID) / 256), 256, 0, stream>>>(A, ei, B);
        k_mlp1<<<(NN + 255) / 256, 256, 0, stream>>>(A, B, g1b1, g1w2, g1b2,
                                                     g2w1, A);
        hipMemsetAsync(B, 0, (size_t)NN * HID * sizeof(float), stream);
        k_scatter<<<(int)(((long long)NE * HID) / 256), 256, 0, stream>>>(A, ei, B);
        k_final<<<(NN + 255) / 256, 256, 0, stream>>>(A, B, g2b1, g2w2, g2b2,
                                                      ro_w, ro_b, out);
    }
}

// Round 13
// 349.813 us; speedup vs baseline: 1.1525x; 1.0396x over previous
//
#include <hip/hip_runtime.h>

#define NN   100000
#define TL   128
#define OC   5
#define KW   7
#define ST   3
#define CL   41          // (128-7)/3+1
#define FLAT 205         // 5*41
#define EMB  32
#define HID  16
#define NE   3200000

#define CLP  44                  // per-channel padded conv length (4-aligned)
#define JP   220                 // OC*CLP, padded flat length
#define JB   55                  // JP/4 float4 blocks
#define WN   8                   // convfc nodes per WAVE (4 waves -> 32/block)
#define SXW  1048                // per-wave s_x slice (8*129=1032, +16 over-read pad)

#define BBUCK  391               // bin buckets (256 nodes each, dst>>8)
#define NPB    14336             // slots per bin bucket (mean fill ~12980, +16 sigma)
#define TILE   4096              // edges per k_bin block
#define NBIN   782               // ceil(NE/TILE)
#define CNODES 64                // nodes per gagg/sort bucket
#define NGB    1563              // ceil(NN/64)
#define NS     2560              // sorted-src capacity per 64-node bucket (mean 2048)
#define SENT   0xFFFFFFFFu       // sentinel slot (real words are < 2^26)

__device__ __forceinline__ void f4add(float4& a, const float4 v) {
    a.x += v.x; a.y += v.y; a.z += v.z; a.w += v.w;
}

// ===========================================================================
// Precompute combined weight wcTl = g1w1 @ fc_w, L-MAJOR and channel-padded
// (r9 format).  bc = g1w1 @ fc_b.  Init bin cursors.  Grid 8 (was 1 block,
// ~15us of single-block latency for trivial work).
// ===========================================================================
__global__ __launch_bounds__(256) void k_prep(
    const float* __restrict__ g1w1, const float* __restrict__ fc_w,
    const float* __restrict__ fc_b,
    float* __restrict__ wcTl, float* __restrict__ bc,
    int* __restrict__ gcur)
{
    const int gid = blockIdx.x * 256 + threadIdx.x;
    const int gs  = gridDim.x * 256;
    for (int idx = gid; idx < HID * JP; idx += gs) {
        int l  = idx / JP;
        int jp = idx - l * JP;
        int c  = jp / CLP;
        int t  = jp - c * CLP;
        float s = 0.f;
        if (t < CL) {
            int j = c * CL + t;
            #pragma unroll
            for (int m = 0; m < EMB; ++m)
                s = fmaf(g1w1[l * EMB + m], fc_w[m * FLAT + j], s);
        }
        wcTl[idx] = s;
    }
    if (gid < HID) {
        float s = 0.f;
        #pragma unroll
        for (int m = 0; m < EMB; ++m)
            s = fmaf(g1w1[gid * EMB + m], fc_b[m], s);
        bc[gid] = s;
    }
    for (int b = gid; b < BBUCK; b += gs)
        gcur[b] = b * NPB;
}

// ===========================================================================
// Fused Conv1d+ReLU+FC(+g1w1), WAVE-SYNCHRONOUS (r9 body verbatim; 68us
// empirical floor across 5 structural variants r6-r10).
// ===========================================================================
__global__ __launch_bounds__(256) void k_convfc(
    const float* __restrict__ x,
    const float* __restrict__ conv_w, const float* __restrict__ conv_b,
    const float* __restrict__ wcTl,  const float* __restrict__ bc,
    float* __restrict__ p1)
{
    __shared__ float s_x[4 * SXW];
    __shared__ float s_h2[4 * WN * JP];
    const int tid  = threadIdx.x;
    const int wv   = tid >> 6;
    const int lane = tid & 63;
    const long long nw = (long long)blockIdx.x * 32 + wv * WN;  // NN=32*3125

    float* sx = s_x  + wv * SXW;
    float* sh = s_h2 + wv * (WN * JP);

    const float4* xv = (const float4*)(x + nw * TL);
    #pragma unroll
    for (int c = 0; c < 4; ++c) {
        int f4  = c * 64 + lane;
        int row = f4 >> 5;
        int c4  = f4 & 31;
        float4 v = xv[f4];
        float* d = sx + row * 129 + c4 * 4;
        d[0] = v.x; d[1] = v.y; d[2] = v.z; d[3] = v.w;
    }
    asm volatile("s_waitcnt lgkmcnt(0)" ::: "memory");

    for (int i = lane; i < 55 * WN; i += 64) {
        int n  = i & (WN - 1);
        int ci = i >> 3;
        int c  = ci / 11;
        int tg = ci - c * 11;
        int t0 = tg * 4;
        const float* xr = sx + n * 129 + t0 * ST;
        float xx[16];
        #pragma unroll
        for (int k = 0; k < 16; ++k) xx[k] = xr[k];
        const float* wr = conv_w + c * KW;
        float w0 = wr[0], w1 = wr[1], w2 = wr[2], w3 = wr[3],
              w4 = wr[4], w5 = wr[5], w6 = wr[6];
        float bb = conv_b[c];
        float4 r;
        r.x = fmaxf(bb + xx[0]*w0 + xx[1]*w1 + xx[2]*w2 + xx[3]*w3
                       + xx[4]*w4 + xx[5]*w5 + xx[6]*w6, 0.f);
        r.y = (t0 + 1 < CL)
            ? fmaxf(bb + xx[3]*w0 + xx[4]*w1 + xx[5]*w2 + xx[6]*w3
                       + xx[7]*w4 + xx[8]*w5 + xx[9]*w6, 0.f) : 0.f;
        r.z = (t0 + 2 < CL)
            ? fmaxf(bb + xx[6]*w0 + xx[7]*w1 + xx[8]*w2 + xx[9]*w3
                       + xx[10]*w4 + xx[11]*w5 + xx[12]*w6, 0.f) : 0.f;
        r.w = (t0 + 3 < CL)
            ? fmaxf(bb + xx[9]*w0 + xx[10]*w1 + xx[11]*w2 + xx[12]*w3
                       + xx[13]*w4 + xx[14]*w5 + xx[15]*w6, 0.f) : 0.f;
        *(float4*)(sh + n * JP + c * CLP + t0) = r;
    }
    asm volatile("s_waitcnt lgkmcnt(0)" ::: "memory");

    const int l = lane & 15;
    const int g = lane >> 4;
    float a0 = bc[l];
    float a1 = a0;
    const float4* wl = (const float4*)(wcTl + l * JP);
    const float4* h0 = (const float4*)(sh + g * JP);
    const float4* h1 = (const float4*)(sh + (g + 4) * JP);
    #pragma unroll 5
    for (int jb = 0; jb < JB; ++jb) {
        float4 w = wl[jb];
        float4 p = h0[jb];
        float4 q = h1[jb];
        a0 = fmaf(p.x, w.x, fmaf(p.y, w.y, fmaf(p.z, w.z, fmaf(p.w, w.w, a0))));
        a1 = fmaf(q.x, w.x, fmaf(q.y, w.y, fmaf(q.z, w.z, fmaf(q.w, w.w, a1))));
    }
    p1[(nw + g)     * HID + l] = a0;
    p1[(nw + g + 4) * HID + l] = a1;
}

// ===========================================================================
// LDS-staged bucket binning v2 (r6 body verbatim, verified).
// ===========================================================================
__global__ __launch_bounds__(256) void k_bin(
    const int* __restrict__ ei, int* __restrict__ gcur,
    unsigned int* __restrict__ gbin)
{
    __shared__ unsigned int s_stage[TILE];
    __shared__ int s_cnt[BBUCK], s_ofs[BBUCK], s_base[BBUCK];
    __shared__ int s_sum[256];

    const int tid = threadIdx.x;
    const int e0  = blockIdx.x * TILE;
    const int cntE = min(TILE, NE - e0);

    for (int b = tid; b < BBUCK; b += 256) s_cnt[b] = 0;
    __syncthreads();

    for (int i = tid; i < cntE; i += 256)
        atomicAdd(&s_cnt[ei[NE + e0 + i] >> 8], 1);
    __syncthreads();

    for (int b = tid; b < BBUCK; b += 256) {
        int c = s_cnt[b];
        s_base[b] = c ? atomicAdd(&gcur[b], (c + 15) & ~15) : 0;
    }

    int v0 = 0, v1 = 0;
    {
        int i0 = tid * 2;
        if (i0     < BBUCK) v0 = s_cnt[i0];
        if (i0 + 1 < BBUCK) v1 = s_cnt[i0 + 1];
    }
    int csum = v0 + v1;
    s_sum[tid] = csum;
    __syncthreads();
    #pragma unroll
    for (int d = 1; d < 256; d <<= 1) {
        int t = (tid >= d) ? s_sum[tid - d] : 0;
        __syncthreads();
        s_sum[tid] += t;
        __syncthreads();
    }
    {
        int run = s_sum[tid] - csum;
        int i0 = tid * 2;
        if (i0     < BBUCK) { s_ofs[i0]     = run; run += v0; }
        if (i0 + 1 < BBUCK) { s_ofs[i0 + 1] = run; }
    }
    __syncthreads();

    for (int i = tid; i < cntE; i += 256) {
        int s = ei[e0 + i];
        int d = ei[NE + e0 + i];
        int b = d >> 8;
        int pos = atomicAdd(&s_ofs[b], 1);
        s_stage[pos] = ((unsigned int)(d & 255) << 17) | (unsigned int)s;
    }
    __syncthreads();

    const int wid = tid >> 6, lane = tid & 63;
    for (int b = wid; b < BBUCK; b += 4) {
        int cnt = s_cnt[b];
        if (!cnt) continue;
        int res = (cnt + 15) & ~15;
        int rdo = s_ofs[b] - cnt;
        int gb  = s_base[b];
        int lim = min(res, b * NPB + NPB - gb);
        for (int j = lane; j < lim; j += 64)
            gbin[(size_t)gb + j] = (j < cnt) ? s_stage[rdo + j] : SENT;
    }
}

// ===========================================================================
// FUSED sort + gather-aggregate + MLP (layer 1).  One block per 64-node
// bucket.  Phase A = k_sort's verified phases (filtered append + hist ->
// 64-scan -> scatter), but the sorted list lands in LDS; goff/gsorted for
// layer 2 are written as COALESCED streams (vs k_sort's scattered stores).
// Phase B = r6 gagg body, srcs read from LDS.  Across blocks, sort-phase
// (streaming/LDS-bound) and gather-phase (random-latency-bound) blocks
// interleave on each CU -> complementary-resource overlap (unlike r11's
// LDS-union fusion which crushed bin occupancy).  LDS ~28KB -> 5 blk/CU.
// ===========================================================================
__global__ __launch_bounds__(256) void k_sgagg1(
    const unsigned int* __restrict__ gbin, const int* __restrict__ gcur,
    const float* __restrict__ feat,
    const float* __restrict__ b1, const float* __restrict__ w2,
    const float* __restrict__ b2, const float* __restrict__ w3,
    int* __restrict__ goff, int* __restrict__ gsorted,
    float* __restrict__ outfeat)
{
    __shared__ unsigned int s_m[NS];             // 10 KB
    __shared__ int s_sorted[NS];                 // 10 KB
    __shared__ float s_acc[CNODES * 16];         // 4 KB
    __shared__ float s_w2[HID * HID], s_w3[HID * HID], s_b1[HID], s_b2[HID];
    __shared__ int s_cnt[CNODES], s_scan[CNODES], s_loc[CNODES];
    __shared__ int s_ofx[CNODES + 1];
    __shared__ int s_n;
    const int tid = threadIdx.x;
    const int b64 = blockIdx.x;
    const int bkt = b64 >> 2, qp = b64 & 3;
    const int nslots = min(gcur[bkt] - bkt * NPB, NPB);
    const unsigned int* run = gbin + (size_t)bkt * NPB;

    s_w2[tid] = w2[tid];
    s_w3[tid] = w3[tid];
    if (tid < HID) { s_b1[tid] = b1[tid]; s_b2[tid] = b2[tid]; }
    if (tid < CNODES) s_cnt[tid] = 0;
    if (tid == 0) s_n = 0;
    __syncthreads();

    // A1: filtered append + histogram in one pass (k_sort-verified)
    for (int i = tid; i < nslots; i += 256) {
        unsigned int w = run[i];
        if (w != SENT && (int)(w >> 23) == qp) {
            int p = atomicAdd(&s_n, 1);
            if (p < NS) {                        // clamp (never hits)
                s_m[p] = w;
                atomicAdd(&s_cnt[(w >> 17) & 63], 1);
            }
        }
    }
    __syncthreads();

    // A2: inclusive Hillis-Steele scan over 64 counters
    if (tid < CNODES) s_scan[tid] = s_cnt[tid];
    __syncthreads();
    #pragma unroll
    for (int d = 1; d < CNODES; d <<= 1) {
        int t = (tid < CNODES && tid >= d) ? s_scan[tid - d] : 0;
        __syncthreads();
        if (tid < CNODES) s_scan[tid] += t;
        __syncthreads();
    }
    if (tid < CNODES) {
        int inc = min(s_scan[tid], NS);
        s_loc[tid] = inc - min(s_cnt[tid], NS);  // exclusive (clamp-safe)
        s_ofx[tid + 1] = inc;
        goff[(size_t)b64 * 65 + tid + 1] = inc;  // layer-2 metadata
    }
    if (tid == 0) { s_ofx[0] = 0; goff[(size_t)b64 * 65] = 0; }
    __syncthreads();

    // A3: scatter srcs into LDS-sorted order
    const int n = min(s_n, NS);
    for (int i = tid; i < n; i += 256) {
        unsigned int w = s_m[i];
        int pos = atomicAdd(&s_loc[(w >> 17) & 63], 1);
        if (pos < NS) s_sorted[pos] = (int)(w & 0x1FFFFu);
    }
    __syncthreads();

    // B0: coalesced gsorted writeout for layer 2 (full-line streaming)
    int* gdst = gsorted + (size_t)b64 * NS;
    for (int i = tid; i < n; i += 256) gdst[i] = s_sorted[i];

    // B1: gather from LDS src list + random feat rows; register accumulate
    const int node = tid >> 2, q4 = tid & 3;
    const float4* pv = (const float4*)feat;
    float4 acc0 = make_float4(0.f, 0.f, 0.f, 0.f);
    float4 acc1 = make_float4(0.f, 0.f, 0.f, 0.f);
    int j = s_ofx[node];
    const int e = s_ofx[node + 1];
    for (; j + 7 < e; j += 8) {
        int s0 = s_sorted[j],     s1 = s_sorted[j + 1];
        int s2 = s_sorted[j + 2], s3 = s_sorted[j + 3];
        int s4 = s_sorted[j + 4], s5 = s_sorted[j + 5];
        int s6 = s_sorted[j + 6], s7 = s_sorted[j + 7];
        float4 v0 = pv[(size_t)s0 * 4 + q4];
        float4 v1 = pv[(size_t)s1 * 4 + q4];
        float4 v2 = pv[(size_t)s2 * 4 + q4];
        float4 v3 = pv[(size_t)s3 * 4 + q4];
        float4 v4 = pv[(size_t)s4 * 4 + q4];
        float4 v5 = pv[(size_t)s5 * 4 + q4];
        float4 v6 = pv[(size_t)s6 * 4 + q4];
        float4 v7 = pv[(size_t)s7 * 4 + q4];
        f4add(acc0, v0); f4add(acc1, v1); f4add(acc0, v2); f4add(acc1, v3);
        f4add(acc0, v4); f4add(acc1, v5); f4add(acc0, v6); f4add(acc1, v7);
    }
    for (; j + 3 < e; j += 4) {
        int s0 = s_sorted[j],     s1 = s_sorted[j + 1];
        int s2 = s_sorted[j + 2], s3 = s_sorted[j + 3];
        float4 v0 = pv[(size_t)s0 * 4 + q4];
        float4 v1 = pv[(size_t)s1 * 4 + q4];
        float4 v2 = pv[(size_t)s2 * 4 + q4];
        float4 v3 = pv[(size_t)s3 * 4 + q4];
        f4add(acc0, v0); f4add(acc1, v1); f4add(acc0, v2); f4add(acc1, v3);
    }
    for (; j < e; ++j)
        f4add(acc0, pv[(size_t)s_sorted[j] * 4 + q4]);
    f4add(acc0, acc1);
    ((float4*)s_acc)[node * 4 + q4] = acc0;
    __syncthreads();

    // B2: per-node MLP epilogue (gagg1-verified)
    const int gn = b64 * CNODES + tid;
    if (tid < CNODES && gn < NN) {
        const float4* fr = (const float4*)(feat + (size_t)gn * HID);
        const float4* sa = (const float4*)(s_acc + tid * 16);
        float t[HID];
        #pragma unroll
        for (int i2 = 0; i2 < 4; ++i2) {
            float4 f = fr[i2], a = sa[i2];
            t[i2*4+0] = fmaxf(f.x + a.x + s_b1[i2*4+0], 0.f);
            t[i2*4+1] = fmaxf(f.y + a.y + s_b1[i2*4+1], 0.f);
            t[i2*4+2] = fmaxf(f.z + a.z + s_b1[i2*4+2], 0.f);
            t[i2*4+3] = fmaxf(f.w + a.w + s_b1[i2*4+3], 0.f);
        }
        float h[HID];
        #pragma unroll
        for (int i2 = 0; i2 < HID; ++i2) {
            float acc = s_b2[i2];
            #pragma unroll
            for (int jj = 0; jj < HID; ++jj) acc += t[jj] * s_w2[i2 * HID + jj];
            h[i2] = fmaxf(acc, 0.f);
        }
        float o[HID];
        #pragma unroll
        for (int i2 = 0; i2 < HID; ++i2) {
            float acc = 0.f;
            #pragma unroll
            for (int jj = 0; jj < HID; ++jj) acc += h[jj] * s_w3[i2 * HID + jj];
            o[i2] = acc;
        }
        float4* po = (float4*)(outfeat + (size_t)gn * HID);
        #pragma unroll
        for (int i2 = 0; i2 < 4; ++i2)
            po[i2] = make_float4(o[i2*4+0], o[i2*4+1], o[i2*4+2], o[i2*4+3]);
    }
}

// ===========================================================================
// Layer-2 gather-aggregate + MLP + readout (r6 body, reads goff/gsorted).
// ===========================================================================
__global__ __launch_bounds__(256) void k_gagg2(
    const float* __restrict__ feat, const int* __restrict__ goff,
    const int* __restrict__ gsorted,
    const float* __restrict__ b1, const float* __restrict__ w2,
    const float* __restrict__ b2, const float* __restrict__ row,
    const float* __restrict__ rob,
    float* __restrict__ out)
{
    __shared__ float s_acc[CNODES * 16];
    __shared__ float s_w2[HID * HID], s_b1[HID], s_b2[HID], s_ro[HID];
    __shared__ int s_off[CNODES + 1];
    const int tid = threadIdx.x;
    const int b   = blockIdx.x;

    s_w2[tid] = w2[tid];
    if (tid < HID) { s_b1[tid] = b1[tid]; s_b2[tid] = b2[tid]; s_ro[tid] = row[tid]; }
    if (tid < CNODES + 1) s_off[tid] = goff[(size_t)b * 65 + tid];
    __syncthreads();

    const int node = tid >> 2, q = tid & 3;
    const int* srcs = gsorted + (size_t)b * NS;
    const float4* pv = (const float4*)feat;
    float4 acc0 = make_float4(0.f, 0.f, 0.f, 0.f);
    float4 acc1 = make_float4(0.f, 0.f, 0.f, 0.f);
    int j = s_off[node];
    const int e = s_off[node + 1];
    for (; j + 7 < e; j += 8) {
        int s0 = srcs[j],     s1 = srcs[j + 1], s2 = srcs[j + 2], s3 = srcs[j + 3];
        int s4 = srcs[j + 4], s5 = srcs[j + 5], s6 = srcs[j + 6], s7 = srcs[j + 7];
        float4 v0 = pv[(size_t)s0 * 4 + q];
        float4 v1 = pv[(size_t)s1 * 4 + q];
        float4 v2 = pv[(size_t)s2 * 4 + q];
        float4 v3 = pv[(size_t)s3 * 4 + q];
        float4 v4 = pv[(size_t)s4 * 4 + q];
        float4 v5 = pv[(size_t)s5 * 4 + q];
        float4 v6 = pv[(size_t)s6 * 4 + q];
        float4 v7 = pv[(size_t)s7 * 4 + q];
        f4add(acc0, v0); f4add(acc1, v1); f4add(acc0, v2); f4add(acc1, v3);
        f4add(acc0, v4); f4add(acc1, v5); f4add(acc0, v6); f4add(acc1, v7);
    }
    for (; j + 3 < e; j += 4) {
        int s0 = srcs[j], s1 = srcs[j + 1], s2 = srcs[j + 2], s3 = srcs[j + 3];
        float4 v0 = pv[(size_t)s0 * 4 + q];
        float4 v1 = pv[(size_t)s1 * 4 + q];
        float4 v2 = pv[(size_t)s2 * 4 + q];
        float4 v3 = pv[(size_t)s3 * 4 + q];
        f4add(acc0, v0); f4add(acc1, v1); f4add(acc0, v2); f4add(acc1, v3);
    }
    for (; j < e; ++j)
        f4add(acc0, pv[(size_t)srcs[j] * 4 + q]);
    f4add(acc0, acc1);
    ((float4*)s_acc)[node * 4 + q] = acc0;
    __syncthreads();

    const int gn = b * CNODES + tid;
    if (tid < CNODES && gn < NN) {
        const float4* fr = (const float4*)(feat + (size_t)gn * HID);
        const float4* sa = (const float4*)(s_acc + tid * 16);
        float t[HID];
        #pragma unroll
        for (int i2 = 0; i2 < 4; ++i2) {
            float4 f = fr[i2], a = sa[i2];
            t[i2*4+0] = fmaxf(f.x + a.x + s_b1[i2*4+0], 0.f);
            t[i2*4+1] = fmaxf(f.y + a.y + s_b1[i2*4+1], 0.f);
            t[i2*4+2] = fmaxf(f.z + a.z + s_b1[i2*4+2], 0.f);
            t[i2*4+3] = fmaxf(f.w + a.w + s_b1[i2*4+3], 0.f);
        }
        float res = rob[0];
        #pragma unroll
        for (int i2 = 0; i2 < HID; ++i2) {
            float acc = s_b2[i2];
            #pragma unroll
            for (int jj = 0; jj < HID; ++jj) acc += t[jj] * s_w2[i2 * HID + jj];
            res += acc * s_ro[i2];
        }
        out[gn] = res;
    }
}

// ===========================================================================
// FALLBACK PATH kernels (workspace too small): per-node embed + atomic scatter
// ===========================================================================
__global__ __launch_bounds__(256) void k_embed(
    const float* __restrict__ x,
    const float* __restrict__ conv_w, const float* __restrict__ conv_b,
    const float* __restrict__ fc_w,   const float* __restrict__ fc_b,
    const float* __restrict__ g1w1,
    float* __restrict__ p1)
{
    __shared__ float s_x[4][TL];
    __shared__ float s_h[4][FLAT + 3];
    __shared__ float s_e[4][EMB];

    const int w    = threadIdx.x >> 6;
    const int lane = threadIdx.x & 63;
    const int node = blockIdx.x * 4 + w;

    const float2* xr = (const float2*)(x + (size_t)node * TL);
    float2 v = xr[lane];
    s_x[w][lane * 2 + 0] = v.x;
    s_x[w][lane * 2 + 1] = v.y;
    __syncthreads();

    for (int o = lane; o < FLAT; o += 64) {
        int c = o / CL;
        int t = o - c * CL;
        float acc = conv_b[c];
        #pragma unroll
        for (int k = 0; k < KW; ++k)
            acc += s_x[w][t * ST + k] * conv_w[c * KW + k];
        s_h[w][o] = fmaxf(acc, 0.f);
    }
    __syncthreads();

    if (lane < EMB) {
        float acc = fc_b[lane];
        const float* wr = fc_w + lane * FLAT;
        for (int j = 0; j < FLAT; ++j)
            acc += s_h[w][j] * wr[j];
        s_e[w][lane] = acc;
    }
    __syncthreads();

    if (lane < HID) {
        float acc = 0.f;
        const float* wr = g1w1 + lane * EMB;
        #pragma unroll
        for (int j = 0; j < EMB; ++j)
            acc += s_e[w][j] * wr[j];
        p1[(size_t)node * HID + lane] = acc;
    }
}

__global__ __launch_bounds__(256) void k_scatter(
    const float* __restrict__ p, const int* __restrict__ ei,
    float* __restrict__ agg)
{
    long long t = (long long)blockIdx.x * 256 + threadIdx.x;
    int e = (int)(t >> 4);
    int k = (int)(t & 15);
    if (e >= NE) return;
    int src = ei[e];
    int dst = ei[NE + e];
    float v = p[(size_t)src * HID + k];
    atomicAdd(agg + (size_t)dst * HID + k, v);
}

__global__ __launch_bounds__(256) void k_mlp1(
    const float* __restrict__ p1, const float* __restrict__ agg,
    const float* __restrict__ b1, const float* __restrict__ w2,
    const float* __restrict__ b2, const float* __restrict__ w3,
    float* __restrict__ p2)
{
    __shared__ float s_w2[HID * HID], s_w3[HID * HID], s_b1[HID], s_b2[HID];
    int tid = threadIdx.x;
    s_w2[tid] = w2[tid];
    s_w3[tid] = w3[tid];
    if (tid < HID) { s_b1[tid] = b1[tid]; s_b2[tid] = b2[tid]; }
    __syncthreads();

    int n = blockIdx.x * 256 + tid;
    if (n >= NN) return;

    float t[HID], h[HID];
    const float4* pa = (const float4*)(p1  + (size_t)n * HID);
    const float4* pb = (const float4*)(agg + (size_t)n * HID);
    #pragma unroll
    for (int i = 0; i < 4; ++i) {
        float4 a = pa[i], b = pb[i];
        t[i*4+0] = fmaxf(a.x + b.x + s_b1[i*4+0], 0.f);
        t[i*4+1] = fmaxf(a.y + b.y + s_b1[i*4+1], 0.f);
        t[i*4+2] = fmaxf(a.z + b.z + s_b1[i*4+2], 0.f);
        t[i*4+3] = fmaxf(a.w + b.w + s_b1[i*4+3], 0.f);
    }
    #pragma unroll
    for (int i = 0; i < HID; ++i) {
        float acc = s_b2[i];
        #pragma unroll
        for (int j = 0; j < HID; ++j) acc += t[j] * s_w2[i * HID + j];
        h[i] = fmaxf(acc, 0.f);
    }
    float o[HID];
    #pragma unroll
    for (int i = 0; i < HID; ++i) {
        float acc = 0.f;
        #pragma unroll
        for (int j = 0; j < HID; ++j) acc += h[j] * s_w3[i * HID + j];
        o[i] = acc;
    }
    float4* po = (float4*)(p2 + (size_t)n * HID);
    #pragma unroll
    for (int i = 0; i < 4; ++i)
        po[i] = make_float4(o[i*4+0], o[i*4+1], o[i*4+2], o[i*4+3]);
}

__global__ __launch_bounds__(256) void k_final(
    const float* __restrict__ p2, const float* __restrict__ agg2,
    const float* __restrict__ b1, const float* __restrict__ w2,
    const float* __restrict__ b2, const float* __restrict__ row,
    const float* __restrict__ rob,
    float* __restrict__ out)
{
    __shared__ float s_w2[HID * HID], s_b1[HID], s_b2[HID], s_ro[HID];
    int tid = threadIdx.x;
    s_w2[tid] = w2[tid];
    if (tid < HID) { s_b1[tid] = b1[tid]; s_b2[tid] = b2[tid]; s_ro[tid] = row[tid]; }
    __syncthreads();

    int n = blockIdx.x * 256 + tid;
    if (n >= NN) return;

    float t[HID];
    const float4* pa = (const float4*)(p2   + (size_t)n * HID);
    const float4* pb = (const float4*)(agg2 + (size_t)n * HID);
    #pragma unroll
    for (int i = 0; i < 4; ++i) {
        float4 a = pa[i], b = pb[i];
        t[i*4+0] = fmaxf(a.x + b.x + s_b1[i*4+0], 0.f);
        t[i*4+1] = fmaxf(a.y + b.y + s_b1[i*4+1], 0.f);
        t[i*4+2] = fmaxf(a.z + b.z + s_b1[i*4+2], 0.f);
        t[i*4+3] = fmaxf(a.w + b.w + s_b1[i*4+3], 0.f);
    }
    float res = rob[0];
    #pragma unroll
    for (int i = 0; i < HID; ++i) {
        float acc = s_b2[i];
        #pragma unroll
        for (int j = 0; j < HID; ++j) acc += t[j] * s_w2[i * HID + j];
        res += acc * s_ro[i];
    }
    out[n] = res;
}

// ===========================================================================
extern "C" void kernel_launch(void* const* d_in, const int* in_sizes, int n_in,
                              void* d_out, int out_size, void* d_ws, size_t ws_size,
                              hipStream_t stream)
{
    const float* x      = (const float*)d_in[0];
    const int*   ei     = (const int*)  d_in[1];
    const float* conv_w = (const float*)d_in[2];
    const float* conv_b = (const float*)d_in[3];
    const float* fc_w   = (const float*)d_in[4];
    const float* fc_b   = (const float*)d_in[5];
    const float* g1w1   = (const float*)d_in[6];
    const float* g1b1   = (const float*)d_in[7];
    const float* g1w2   = (const float*)d_in[8];
    const float* g1b2   = (const float*)d_in[9];
    const float* g2w1   = (const float*)d_in[10];
    const float* g2b1   = (const float*)d_in[11];
    const float* g2w2   = (const float*)d_in[12];
    const float* g2b2   = (const float*)d_in[13];
    const float* ro_w   = (const float*)d_in[14];
    const float* ro_b   = (const float*)d_in[15];
    float* out = (float*)d_out;

    // workspace layout:
    //   A       [NN*HID] f32        p1 (projected features)
    //   B       [NN*HID] f32        p2 (layer-2 projected features)
    //   wcTl    [HID*JP] f32        combined fc+g1w1 weight, l-major padded
    //   bc      [16] f32            combined bias
    //   gcur    [BBUCK] i32         bin cursors
    //   gbin    [BBUCK*NPB] u32     packed (local_dst<<17)|src per bin bucket
    //   goff    [NGB*65] i32        per-node offsets within gagg bucket
    //   gsorted [NGB*NS] i32        dst-sorted src ids per gagg bucket
    float* A    = (float*)d_ws;
    float* B    = A + (size_t)NN * HID;
    float* wcTl = B + (size_t)NN * HID;
    float* bc   = wcTl + (size_t)HID * JP;
    int*   gcur = (int*)(bc + 16);
    unsigned int* gbin = (unsigned int*)(gcur + BBUCK);
    int*   goff    = (int*)(gbin + (size_t)BBUCK * NPB);
    int*   gsorted = goff + (size_t)NGB * 65;
    const size_t need = (size_t)((char*)(gsorted + (size_t)NGB * NS) - (char*)d_ws);

    if (ws_size >= need) {
        k_prep<<<8, 256, 0, stream>>>(g1w1, fc_w, fc_b, wcTl, bc, gcur);
        k_convfc<<<NN / 32, 256, 0, stream>>>(x, conv_w, conv_b, wcTl, bc, A);
        k_bin<<<NBIN, 256, 0, stream>>>(ei, gcur, gbin);
        // GIN layer 1: fused sort + atomic-free gather + MLP + layer-2 proj
        k_sgagg1<<<NGB, 256, 0, stream>>>(gbin, gcur, A, g1b1, g1w2, g1b2,
                                          g2w1, goff, gsorted, B);
        // GIN layer 2: atomic-free gather + MLP + readout
        k_gagg2<<<NGB, 256, 0, stream>>>(B, goff, gsorted, g2b1, g2w2, g2b2,
                                         ro_w, ro_b, out);
    } else {
        // --- fallback: fused per-node embed + atomic scatter ---
        k_embed<<<NN / 4, 256, 0, stream>>>(x, conv_w, conv_b, fc_w, fc_b,
                                            g1w1, A);
        hipMemsetAsync(B, 0, (size_t)NN * HID * sizeof(float), stream);
        k_scatter<<<(int)(((long long)NE * HID) / 256), 256, 0, stream>>>(A, ei, B);
        k_mlp1<<<(NN + 255) / 256, 256, 0, stream>>>(A, B, g1b1, g1w2, g1b2,
                                                     g2w1, A);
        hipMemsetAsync(B, 0, (size_t)NN * HID * sizeof(float), stream);
        k_scatter<<<(int)(((long long)NE * HID) / 256), 256, 0, stream>>>(A, ei, B);
        k_final<<<(NN + 255) / 256, 256, 0, stream>>>(A, B, g2b1, g2w2, g2b2,
                                                      ro_w, ro_b, out);
    }
}